// Round 4
// baseline (276.393 us; speedup 1.0000x reference)
//
#include <hip/hip_runtime.h>
#include <hip/hip_bf16.h>

typedef unsigned short ushort_t;
typedef __attribute__((ext_vector_type(8))) short short8;   // 8 x bf16 (4 VGPRs)
typedef __attribute__((ext_vector_type(4))) float floatx4;  // MFMA acc

#define BATCH 4
#define SEQ   2048
#define CH    1024
#define NHEAD 16
#define HSZ   64
#define MROWS (BATCH * SEQ)  // 8192

// async global->LDS, 16B per lane; LDS dest = wave-uniform base + lane*16
#define GLD16(gptr, lptr) \
    __builtin_amdgcn_global_load_lds((const __attribute__((address_space(1))) unsigned int*)(gptr), \
                                     (__attribute__((address_space(3))) unsigned int*)(lptr), 16, 0, 0)

__device__ inline ushort_t f2b(float f) {
    __hip_bfloat16 h = __float2bfloat16(f);
    return *(ushort_t*)&h;
}
__device__ inline float b2f(ushort_t u) {
    return __bfloat162float(*(__hip_bfloat16*)&u);
}

// raw v_exp_f32: OCML exp2f adds a denormal-range guard (~5 VALU insts/call)
// we don't need — masked inputs are -1e30 and raw v_exp_f32(-1e30) = +0.
__device__ __forceinline__ float fast_exp2(float x) {
#if __has_builtin(__builtin_amdgcn_exp2f)
    return __builtin_amdgcn_exp2f(x);
#else
    float r; asm("v_exp_f32 %0, %1" : "=v"(r) : "v"(x)); return r;
#endif
}

// -------- dtype detect (parallel): *flag = 1 if x is bf16, 0 if f32 --------------
__global__ void detect_dtype(const ushort_t* __restrict__ x, int* __restrict__ flag) {
    int cnt = 0;
    #pragma unroll
    for (int i = 0; i < 8; i++) {
        const int e = (x[2 * (threadIdx.x * 8 + i)] >> 7) & 0xFF;
        const unsigned long long m = __ballot(e >= 100 && e <= 140);
        cnt += (int)__popcll(m);
    }
    if (threadIdx.x == 0) *flag = (cnt >= 400) ? 1 : 0;
}

// -------- 4x weight transpose+convert: in[k][n] -> out bf16 [n][k] ---------------
__global__ __launch_bounds__(256) void convert_wt4(const void* w0, const void* w1,
                                                   const void* w2, const void* w3,
                                                   ushort_t* o0, ushort_t* o1,
                                                   ushort_t* o2, ushort_t* o3,
                                                   const int* __restrict__ flag) {
    __shared__ ushort_t tile[32][33];
    const void* in = (blockIdx.z == 0) ? w0 : (blockIdx.z == 1) ? w1 : (blockIdx.z == 2) ? w2 : w3;
    ushort_t*  out = (blockIdx.z == 0) ? o0 : (blockIdx.z == 1) ? o1 : (blockIdx.z == 2) ? o2 : o3;
    const int am = *flag;
    const int bx = blockIdx.x * 32, by = blockIdx.y * 32;
    const int tx = threadIdx.x & 31, ty = threadIdx.x >> 5;
    #pragma unroll
    for (int r = ty; r < 32; r += 8) {
        const size_t idx = (size_t)(by + r) * CH + bx + tx;
        tile[r][tx] = am ? ((const ushort_t*)in)[idx] : f2b(((const float*)in)[idx]);
    }
    __syncthreads();
    #pragma unroll
    for (int r = ty; r < 32; r += 8)
        out[(size_t)(bx + r) * CH + by + tx] = tile[tx][r];
}

// -------- 4x bias convert --------------------------------------------------------
__global__ void convert_bias4(const void* b0, const void* b1, const void* b2, const void* b3,
                              ushort_t* __restrict__ out, const int* __restrict__ flag) {
    const int i = blockIdx.x * 256 + threadIdx.x;  // 0..4095
    const int m = i >> 10, idx = i & 1023;
    const void* in = (m == 0) ? b0 : (m == 1) ? b1 : (m == 2) ? b2 : b3;
    out[i] = (*flag) ? ((const ushort_t*)in)[idx] : f2b(((const float*)in)[idx]);
}

// -------- x convert: flat fp32/bf16 -> bf16, 8 elems/thread ----------------------
__global__ __launch_bounds__(256) void convert_x(const void* __restrict__ in,
                                                 ushort_t* __restrict__ out,
                                                 const int* __restrict__ flag) {
    const int i = (blockIdx.x * 256 + threadIdx.x) * 8;
    if (*flag) {
        *(float4*)&out[i] = *(const float4*)&((const ushort_t*)in)[i];
    } else {
        const float* p = (const float*)in + i;
        float4 f0 = *(const float4*)p;
        float4 f1 = *(const float4*)(p + 4);
        ushort_t t[8] = {f2b(f0.x), f2b(f0.y), f2b(f0.z), f2b(f0.w),
                         f2b(f1.x), f2b(f1.y), f2b(f1.z), f2b(f1.w)};
        *(float4*)&out[i] = *(const float4*)t;
    }
}

// ============ 256x256 8-wave 8-phase QKV GEMM (T2+T3+T4+T5, R3 post-mortem) ======
// R3 proved counted-vmcnt on the 2-phase 128^2 loop is NULL (711 TF, matches the
// documented 2-phase band). This is the 256^2 phase-interleaved template:
// BK=64, 512 thr = 8 waves (2M x 4N), wave tile 128x64, acc[8][4], LDS 128KB
// (2 bufs x 256x64 x {A,B}). 4 phases per K-tile; phase p: {stage ONE half-tile
// (128 rows, 2xGLD16/thread) of tile t+1 -> ds_read a-frags m={2p,2p+1} (phase 0
// also all 8 b-frags) -> barrier -> setprio(1) 16 MFMA setprio(0) -> barrier}.
// vmcnt(2) ONCE per tile at phase 0 (after issuing the next-tile stage), never 0
// except the last tile.
// Sync-safety: t+1 stages write buf (t+1)&1 whose last reads (tile t-1) finished
// before the barrier ending tile t-1 (per-wave lgkm auto-wait before MFMA + block
// barrier). Reads of tile t are gated by {all waves' vmcnt(2) -> barrier}:
// outstanding = t's 8 loads + 2 just-issued => t's 8 proven landed chip-wide.
// End-of-tile barrier stops tile t+2 stage-issues (buf t&1) passing tile-t reads.
// All branches block-uniform -> no barrier divergence. K-accumulation order per
// fragment identical to the old kloop64 (t asc, kk asc) -> bitwise-same outputs.
#define STG(Sbuf, src, base0, h, tt) do {                                              \
    const int r0_ = (h) * 128 + wave * 8 + lrow;                                       \
    GLD16((src) + (size_t)((base0) + r0_) * CH + (tt) * 64 + gu * 8,                   \
          &Sbuf[(tt) & 1][r0_ * 64 + lu * 8]);                                         \
    GLD16((src) + (size_t)((base0) + r0_ + 64) * CH + (tt) * 64 + gu * 8,              \
          &Sbuf[(tt) & 1][(r0_ + 64) * 64 + lu * 8]);                                  \
} while (0)

__global__ __launch_bounds__(512) void gemm_qkv8(const ushort_t* __restrict__ A,
                                                 const ushort_t* __restrict__ Bt,
                                                 const ushort_t* __restrict__ bias,
                                                 ushort_t* __restrict__ Qb,
                                                 ushort_t* __restrict__ Kb,
                                                 ushort_t* __restrict__ Vt,
                                                 float qscale) {
    __shared__ __align__(16) ushort_t As[2][256 * 64];   // 64 KB
    __shared__ __align__(16) ushort_t Bs[2][256 * 64];   // 64 KB
    const int tid = threadIdx.x;
    const int lane = tid & 63, wave = tid >> 6;
    const int wm = wave >> 2, wn = wave & 3;             // 2M x 4N wave grid
    const int lane15 = lane & 15, quad = lane >> 4;
    const int s7 = lane15 & 7;                           // read-side swizzle key
    const int lrow = lane >> 3, lu = lane & 7;           // staging row/unit
    const int gu = lu ^ lrow;                            // swizzled source unit
    // XCD-chunked bijective swizzle (grid 384, 384%8==0)
    const int cpx = (int)gridDim.x >> 3;
    const int bidl = ((int)blockIdx.x & 7) * cpx + ((int)blockIdx.x >> 3);
    const int rowblk = bidl / 12, colblk = bidl - rowblk * 12;
    const int row0 = rowblk * 256, col0 = colblk * 256;
    const int seg = col0 >> 10;                          // 0=Q 1=K 2=V (uniform)

    floatx4 acc[8][4];
    #pragma unroll
    for (int m = 0; m < 8; m++)
        #pragma unroll
        for (int n = 0; n < 4; n++) acc[m][n] = {0.f, 0.f, 0.f, 0.f};

    // prologue: stage tile 0's 4 half-tiles
    STG(Bs, Bt, col0, 0, 0); STG(Bs, Bt, col0, 1, 0);
    STG(As, A, row0, 0, 0);  STG(As, A, row0, 1, 0);

    for (int t = 0; t < 16; ++t) {
        const ushort_t* Ab = &As[t & 1][wm * 128 * 64];
        const ushort_t* Bb = &Bs[t & 1][wn * 64 * 64];
        const bool pf = (t + 1 < 16);
        short8 bfr[4][2];
        #pragma unroll
        for (int p = 0; p < 4; ++p) {
            if (p == 0) {
                if (pf) { STG(Bs, Bt, col0, 0, t + 1); asm volatile("s_waitcnt vmcnt(2)" ::: "memory"); }
                else    {                              asm volatile("s_waitcnt vmcnt(0)" ::: "memory"); }
            } else if (pf) {
                if (p == 1)      STG(Bs, Bt, col0, 1, t + 1);
                else if (p == 2) STG(As, A, row0, 0, t + 1);
                else             STG(As, A, row0, 1, t + 1);
            }
            __builtin_amdgcn_s_barrier();
            if (p == 0) {
                #pragma unroll
                for (int n = 0; n < 4; ++n) {
                    const int br = n * 16 + lane15;
                    bfr[n][0] = *(const short8*)&Bb[br * 64 + ((quad ^ s7) * 8)];
                    bfr[n][1] = *(const short8*)&Bb[br * 64 + (((quad + 4) ^ s7) * 8)];
                }
            }
            short8 af[2][2];
            #pragma unroll
            for (int mi = 0; mi < 2; ++mi) {
                const int ar = (p * 2 + mi) * 16 + lane15;
                af[mi][0] = *(const short8*)&Ab[ar * 64 + ((quad ^ s7) * 8)];
                af[mi][1] = *(const short8*)&Ab[ar * 64 + (((quad + 4) ^ s7) * 8)];
            }
            __builtin_amdgcn_s_setprio(1);
            #pragma unroll
            for (int mi = 0; mi < 2; ++mi)
                #pragma unroll
                for (int n = 0; n < 4; ++n) {
                    acc[p * 2 + mi][n] = __builtin_amdgcn_mfma_f32_16x16x32_bf16(af[mi][0], bfr[n][0], acc[p * 2 + mi][n], 0, 0, 0);
                    acc[p * 2 + mi][n] = __builtin_amdgcn_mfma_f32_16x16x32_bf16(af[mi][1], bfr[n][1], acc[p * 2 + mi][n], 0, 0, 0);
                }
            __builtin_amdgcn_s_setprio(0);
            __builtin_amdgcn_s_barrier();
        }
    }

    // epilogue: same per-segment stores as the 128^2 version
    #pragma unroll
    for (int n = 0; n < 4; ++n) {
        const int col = col0 + wn * 64 + n * 16 + lane15;
        const float bv = b2f(bias[col]);
        #pragma unroll
        for (int m = 0; m < 8; ++m) {
            const int rowb = row0 + wm * 128 + m * 16 + quad * 4;
            if (seg == 0) {
                #pragma unroll
                for (int r = 0; r < 4; r++)
                    Qb[(size_t)(rowb + r) * CH + col] = f2b((acc[m][n][r] + bv) * qscale);
            } else if (seg == 1) {
                const int c = col - 1024;
                #pragma unroll
                for (int r = 0; r < 4; r++)
                    Kb[(size_t)(rowb + r) * CH + c] = f2b(acc[m][n][r] + bv);
            } else {
                const int c = col - 2048;
                ushort_t pk[4];
                #pragma unroll
                for (int r = 0; r < 4; r++) pk[r] = f2b(acc[m][n][r] + bv);
                const int bb = rowb >> 11, tc = rowb & 2047;
                *(uint2*)&Vt[((size_t)bb * 1024 + c) * 2048 + tc] = *(const uint2*)pk;
            }
        }
    }
}

// -------- BK=64 XOR-swizzled K-loop (R2 form, single-buffer: gemm_bt only) -------
__device__ __forceinline__ void kloop64(const ushort_t* __restrict__ A,
                                        const ushort_t* __restrict__ Bt,
                                        int K, int row0, int col0,
                                        ushort_t* As, ushort_t* Bs,
                                        floatx4 acc[4][4],
                                        int lane, int wave) {
    const int lane15 = lane & 15, quad = lane >> 4;
    const int wr = (wave >> 1) * 64, wc = (wave & 1) * 64;
    const int rg = lane >> 3;                       // row within 8-row group
    const int cg = (lane & 7) ^ rg;                 // staged (permuted) chunk
    const int s7 = lane15 & 7;                      // read-side swizzle key
    for (int k0 = 0; k0 < K; k0 += 64) {
        #pragma unroll
        for (int l = wave; l < 16; l += 4) {        // 16 wave-loads each (8 rows x 1KB)
            GLD16(A  + (size_t)(row0 + l * 8 + rg) * K + k0 + cg * 8, &As[l * 512]);
            GLD16(Bt + (size_t)(col0 + l * 8 + rg) * K + k0 + cg * 8, &Bs[l * 512]);
        }
        __syncthreads();
        #pragma unroll
        for (int kk = 0; kk < 2; kk++) {
            short8 af[4], bfr[4];
            #pragma unroll
            for (int i = 0; i < 4; i++)
                af[i] = *(const short8*)&As[(wr + i * 16 + lane15) * 64 + (((kk * 4 + quad) ^ s7) * 8)];
            #pragma unroll
            for (int j = 0; j < 4; j++)
                bfr[j] = *(const short8*)&Bs[(wc + j * 16 + lane15) * 64 + (((kk * 4 + quad) ^ s7) * 8)];
            #pragma unroll
            for (int i = 0; i < 4; i++)
                #pragma unroll
                for (int j = 0; j < 4; j++)
                    acc[i][j] = __builtin_amdgcn_mfma_f32_16x16x32_bf16(af[i], bfr[j], acc[i][j], 0, 0, 0);
        }
        __syncthreads();
    }
}

// ---------------- output GEMM: Out[M,N] = A @ Bt^T + bias (fp32 or bf16 out) -----
__global__ __launch_bounds__(256) void gemm_bt(const ushort_t* __restrict__ A,
                                               const ushort_t* __restrict__ Bt,
                                               const ushort_t* __restrict__ bias,
                                               void* __restrict__ Out,
                                               int M, int N, int K,
                                               const int* __restrict__ oflag) {
    __shared__ __align__(16) ushort_t As[128 * 64];
    __shared__ __align__(16) ushort_t Bs[128 * 64];
    const int om = *oflag;
    const int tid = threadIdx.x;
    const int lane = tid & 63, wave = tid >> 6;
    const int lane15 = lane & 15, quad = lane >> 4;
    const int wr = (wave >> 1) * 64, wc = (wave & 1) * 64;
    const int row0 = blockIdx.x * 128, col0 = blockIdx.y * 128;

    floatx4 acc[4][4];
    #pragma unroll
    for (int i = 0; i < 4; i++)
        #pragma unroll
        for (int j = 0; j < 4; j++) acc[i][j] = {0.f, 0.f, 0.f, 0.f};

    kloop64(A, Bt, K, row0, col0, As, Bs, acc, lane, wave);

    #pragma unroll
    for (int j = 0; j < 4; j++) {
        const int col = col0 + wc + j * 16 + lane15;
        const float bv = b2f(bias[col]);
        #pragma unroll
        for (int i = 0; i < 4; i++) {
            const int rowb = row0 + wr + i * 16 + quad * 4;
            #pragma unroll
            for (int r = 0; r < 4; r++) {
                const float val = acc[i][j][r] + bv;
                const size_t idx = (size_t)(rowb + r) * N + col;
                if (om) ((ushort_t*)Out)[idx] = f2b(val);
                else    ((float*)Out)[idx] = val;
            }
        }
    }
}

// ---------------- flash attention (round-6 structure + S^T write path) -----------
// Keep: K/V dbuf, one barrier per tile, XCD-local (b,h) in bid&63, ones-MFMA
// rowsum, exp2 with scale folded into Q, swizzled K/V staging, Ps LDS round
// trip (decouples S from PV across waves). DO NOT add a second
// __launch_bounds__ arg (round-7 spill).
//
// R1 (kept): fast_exp2 raw v_exp_f32; Ps stride-64 4-bit XOR chunk swizzle
// (b64 writes and split-b64 PV reads both bank-conflict-free). Verified R2:
// attn dropped out of top-5 (<71.5 us, was 75.5).
__global__ __launch_bounds__(256) void attn_fwd(ushort_t* __restrict__ QY,
                                                const ushort_t* __restrict__ K,
                                                const ushort_t* __restrict__ Vt) {
    __shared__ __align__(16) ushort_t Ks[2][64 * 64];    // [buf][kv][d], swizzled
    __shared__ __align__(16) ushort_t Vs[2][64 * 64];    // [buf][d][kv], swizzled
    __shared__ __align__(16) ushort_t Ps[4 * 32 * 64];   // per-wave [q=32][kv=64], XOR-swizzled
    const int tid = threadIdx.x;
    const int lane = tid & 63, wave = tid >> 6;
    const int lane15 = lane & 15, quad = lane >> 4;
    const int sw = lane15 & 7;                            // read-side swizzle key
    const int bid = blockIdx.x;
    const int hb = bid & 63, qslot = bid >> 6;
    const int qb = 15 - qslot;
    const int h = hb & 15, b = hb >> 4;
    const int q0 = qb * 128;
    const size_t baseR = (size_t)b * SEQ * CH + h * HSZ;      // +t*CH+d (Q,K,Y)
    const size_t baseV = ((size_t)b * 1024 + h * HSZ) * SEQ;  // +d*SEQ+t (Vt)
    const int rg = lane >> 3, cg = (lane & 7) ^ rg;           // staging swizzle
    const int psBase = wave * 2048;                           // per-wave Ps region

    short8 qf[2][2];
    #pragma unroll
    for (int mm = 0; mm < 2; mm++) {
        const ushort_t* qp = QY + baseR + (size_t)(q0 + wave * 32 + mm * 16 + lane15) * CH + quad * 8;
        qf[mm][0] = *(const short8*)qp;
        qf[mm][1] = *(const short8*)(qp + 32);
    }
    const short8 kOnes = (short8)(short)0x3F80;  // bf16 1.0 x8

    floatx4 o[2][5];  // [mm][0..3]=O d-chunks, [4]=l (rowsum)
    #pragma unroll
    for (int mm = 0; mm < 2; mm++)
        #pragma unroll
        for (int j = 0; j < 5; j++) o[mm][j] = {0.f, 0.f, 0.f, 0.f};

    const int nkt = 2 * qb + 2;
    // preamble: stage tile 0 into buf 0
    #pragma unroll
    for (int l = wave; l < 8; l += 4) {
        GLD16(K  + baseR + (size_t)(l * 8 + rg) * CH + cg * 8, &Ks[0][l * 512]);
        GLD16(Vt + baseV + (size_t)(l * 8 + rg) * SEQ + cg * 8, &Vs[0][l * 512]);
    }

    for (int kt = 0; kt < nkt; kt++) {
        __syncthreads();  // staging of kt landed; all waves done with buf kt^1
        const int cur = kt & 1;
        if (kt + 1 < nkt) {
            const int kv1 = (kt + 1) * 64, nb = cur ^ 1;
            #pragma unroll
            for (int l = wave; l < 8; l += 4) {
                GLD16(K  + baseR + (size_t)(kv1 + l * 8 + rg) * CH + cg * 8, &Ks[nb][l * 512]);
                GLD16(Vt + baseV + (size_t)(l * 8 + rg) * SEQ + kv1 + cg * 8, &Vs[nb][l * 512]);
            }
        }
        const int kv0 = kt * 64;
        const int masked = (kt >= 2 * qb);

        // K fragments shared by both q-groups: a-frag of S^T = K[kv][d]
        short8 kf[4][2];
        #pragma unroll
        for (int g = 0; g < 4; g++) {
            kf[g][0] = *(const short8*)&Ks[cur][(g * 16 + lane15) * 64 + ((quad ^ sw) * 8)];
            kf[g][1] = *(const short8*)&Ks[cur][(g * 16 + lane15) * 64 + (((quad + 4) ^ sw) * 8)];
        }

        #pragma unroll
        for (int mm = 0; mm < 2; mm++) {
            const int qrow = q0 + wave * 32 + mm * 16 + lane15;
            const int rowOff = psBase + (mm * 16 + lane15) * 64;
            #pragma unroll
            for (int g = 0; g < 4; g++) {
                // z = S^T[kv = kv0+g*16+quad*4+r][q = qrow]
                floatx4 z = {0.f, 0.f, 0.f, 0.f};
                z = __builtin_amdgcn_mfma_f32_16x16x32_bf16(kf[g][0], qf[mm][0], z, 0, 0, 0);
                z = __builtin_amdgcn_mfma_f32_16x16x32_bf16(kf[g][1], qf[mm][1], z, 0, 0, 0);
                if (masked) {
                    #pragma unroll
                    for (int r = 0; r < 4; r++) {
                        const int col = kv0 + g * 16 + quad * 4 + r;
                        z[r] = (col <= qrow) ? z[r] : -1e30f;
                    }
                }
                // p = 2^z (raw v_exp_f32: 2^-1e30 -> 0 for masked lanes)
                const float p0 = fast_exp2(z[0]), p1 = fast_exp2(z[1]);
                const float p2 = fast_exp2(z[2]), p3 = fast_exp2(z[3]);
                unsigned int lo, hi;
                asm("v_cvt_pk_bf16_f32 %0, %1, %2" : "=v"(lo) : "v"(p0), "v"(p1));
                asm("v_cvt_pk_bf16_f32 %0, %1, %2" : "=v"(hi) : "v"(p2), "v"(p3));
                uint2 w; w.x = lo; w.y = hi;
                // logical 8B-chunk c = g*4+quad; physical = c ^ (row&15)
                *(uint2*)&Ps[rowOff + (((g * 4 + quad) ^ lane15) * 4)] = w;
            }
        }
        // Ps wave-private: lgkmcnt auto-wait orders write->read, no barrier

        #pragma unroll
        for (int kk = 0; kk < 2; kk++) {
            #pragma unroll
            for (int mm = 0; mm < 2; mm++) {
                // A-frag: logical chunks c0 = kk*8+quad*2, c0+1; swizzled apart
                const int rowOff = psBase + (mm * 16 + lane15) * 64;
                const int c0 = kk * 8 + quad * 2;
                short8 a;
                ((uint2*)&a)[0] = *(const uint2*)&Ps[rowOff + (((c0    ) ^ lane15) * 4)];
                ((uint2*)&a)[1] = *(const uint2*)&Ps[rowOff + (((c0 + 1) ^ lane15) * 4)];
                #pragma unroll
                for (int jn = 0; jn < 4; jn++) {
                    short8 bb = *(const short8*)&Vs[cur][(jn * 16 + lane15) * 64 + (((kk * 4 + quad) ^ sw) * 8)];
                    o[mm][jn] = __builtin_amdgcn_mfma_f32_16x16x32_bf16(a, bb, o[mm][jn], 0, 0, 0);
                }
                o[mm][4] = __builtin_amdgcn_mfma_f32_16x16x32_bf16(a, kOnes, o[mm][4], 0, 0, 0);
            }
        }
    }

    // epilogue: Y = O / l
    #pragma unroll
    for (int mm = 0; mm < 2; mm++)
        #pragma unroll
        for (int r = 0; r < 4; r++) {
            const int qrow = q0 + wave * 32 + mm * 16 + quad * 4 + r;
            const float rinv = 1.0f / fmaxf(o[mm][4][r], 1e-30f);
            #pragma unroll
            for (int jn = 0; jn < 4; jn++)
                QY[baseR + (size_t)qrow * CH + jn * 16 + lane15] = f2b(o[mm][jn][r] * rinv);
        }
}

extern "C" void kernel_launch(void* const* d_in, const int* in_sizes, int n_in,
                              void* d_out, int out_size, void* d_ws, size_t ws_size,
                              hipStream_t stream) {
    const void* x  = d_in[0];
    const void* Wk = d_in[1];
    const void* bk = d_in[2];
    const void* Wq = d_in[3];
    const void* bq = d_in[4];
    const void* Wv = d_in[5];
    const void* bv = d_in[6];
    const void* Wo = d_in[7];
    const void* bo = d_in[8];

    ushort_t* ws    = (ushort_t*)d_ws;
    int*      flag  = (int*)d_ws;
    ushort_t* biasC = ws + 2048;                    // 4x1024: q,k,v,o (contiguous)
    ushort_t* WqkvT = ws + 32768;                   // 3x1M contiguous: q,k,v
    ushort_t* WoT   = WqkvT + 3u * (1u << 20);
    ushort_t* xb    = ws + 4227072;                 // 8M elems bf16
    ushort_t* Qb    = ws + 12615680;                // 8M elems (becomes Y)
    ushort_t* Kb    = (ushort_t*)d_out;             // d_out scratch until final GEMM
    ushort_t* VtB   = Kb + (size_t)MROWS * CH;

    detect_dtype<<<1, 64, 0, stream>>>((const ushort_t*)x, flag);

    dim3 tgrid(32, 32, 4);
    convert_wt4<<<tgrid, 256, 0, stream>>>(Wq, Wk, Wv, Wo,
                                           WqkvT, WqkvT + (1u << 20), WqkvT + 2u * (1u << 20), WoT, flag);
    convert_bias4<<<16, 256, 0, stream>>>(bq, bk, bv, bo, biasC, flag);
    convert_x<<<MROWS * CH / (256 * 8), 256, 0, stream>>>(x, xb, flag);

    // scale = (1/sqrt(64)) * log2(e), folded into Q so attention uses exp2
    gemm_qkv8<<<dim3(384), 512, 0, stream>>>(xb, WqkvT, biasC, Qb, Kb, VtB, 0.1803368801f);

    attn_fwd<<<dim3(1024), 256, 0, stream>>>(Qb, Kb, VtB);

    dim3 ogrid(MROWS / 128, CH / 128);
    gemm_bt<<<ogrid, 256, 0, stream>>>(Qb, WoT, biasC + 3072, d_out, MROWS, CH, CH, flag);
}

// Round 5
// 243.822 us; speedup vs baseline: 1.1336x; 1.1336x over previous
//
#include <hip/hip_runtime.h>
#include <hip/hip_bf16.h>

typedef unsigned short ushort_t;
typedef __attribute__((ext_vector_type(8))) short short8;   // 8 x bf16 (4 VGPRs)
typedef __attribute__((ext_vector_type(4))) float floatx4;  // MFMA acc

#define BATCH 4
#define SEQ   2048
#define CH    1024
#define NHEAD 16
#define HSZ   64
#define MROWS (BATCH * SEQ)  // 8192

// async global->LDS, 16B per lane; LDS dest = wave-uniform base + lane*16
#define GLD16(gptr, lptr) \
    __builtin_amdgcn_global_load_lds((const __attribute__((address_space(1))) unsigned int*)(gptr), \
                                     (__attribute__((address_space(3))) unsigned int*)(lptr), 16, 0, 0)

__device__ inline ushort_t f2b(float f) {
    __hip_bfloat16 h = __float2bfloat16(f);
    return *(ushort_t*)&h;
}
__device__ inline float b2f(ushort_t u) {
    return __bfloat162float(*(__hip_bfloat16*)&u);
}

// raw v_exp_f32: OCML exp2f adds a denormal-range guard (~5 VALU insts/call)
// we don't need — masked inputs are -1e30 and raw v_exp_f32(-1e30) = +0.
__device__ __forceinline__ float fast_exp2(float x) {
#if __has_builtin(__builtin_amdgcn_exp2f)
    return __builtin_amdgcn_exp2f(x);
#else
    float r; asm("v_exp_f32 %0, %1" : "=v"(r) : "v"(x)); return r;
#endif
}

// -------- dtype detect (parallel): *flag = 1 if x is bf16, 0 if f32 --------------
__global__ void detect_dtype(const ushort_t* __restrict__ x, int* __restrict__ flag) {
    int cnt = 0;
    #pragma unroll
    for (int i = 0; i < 8; i++) {
        const int e = (x[2 * (threadIdx.x * 8 + i)] >> 7) & 0xFF;
        const unsigned long long m = __ballot(e >= 100 && e <= 140);
        cnt += (int)__popcll(m);
    }
    if (threadIdx.x == 0) *flag = (cnt >= 400) ? 1 : 0;
}

// -------- 4x weight transpose+convert: in[k][n] -> out bf16 [n][k] ---------------
__global__ __launch_bounds__(256) void convert_wt4(const void* w0, const void* w1,
                                                   const void* w2, const void* w3,
                                                   ushort_t* o0, ushort_t* o1,
                                                   ushort_t* o2, ushort_t* o3,
                                                   const int* __restrict__ flag) {
    __shared__ ushort_t tile[32][33];
    const void* in = (blockIdx.z == 0) ? w0 : (blockIdx.z == 1) ? w1 : (blockIdx.z == 2) ? w2 : w3;
    ushort_t*  out = (blockIdx.z == 0) ? o0 : (blockIdx.z == 1) ? o1 : (blockIdx.z == 2) ? o2 : o3;
    const int am = *flag;
    const int bx = blockIdx.x * 32, by = blockIdx.y * 32;
    const int tx = threadIdx.x & 31, ty = threadIdx.x >> 5;
    #pragma unroll
    for (int r = ty; r < 32; r += 8) {
        const size_t idx = (size_t)(by + r) * CH + bx + tx;
        tile[r][tx] = am ? ((const ushort_t*)in)[idx] : f2b(((const float*)in)[idx]);
    }
    __syncthreads();
    #pragma unroll
    for (int r = ty; r < 32; r += 8)
        out[(size_t)(bx + r) * CH + by + tx] = tile[tx][r];
}

// -------- 4x bias convert --------------------------------------------------------
__global__ void convert_bias4(const void* b0, const void* b1, const void* b2, const void* b3,
                              ushort_t* __restrict__ out, const int* __restrict__ flag) {
    const int i = blockIdx.x * 256 + threadIdx.x;  // 0..4095
    const int m = i >> 10, idx = i & 1023;
    const void* in = (m == 0) ? b0 : (m == 1) ? b1 : (m == 2) ? b2 : b3;
    out[i] = (*flag) ? ((const ushort_t*)in)[idx] : f2b(((const float*)in)[idx]);
}

// -------- x convert: flat fp32/bf16 -> bf16, 8 elems/thread ----------------------
__global__ __launch_bounds__(256) void convert_x(const void* __restrict__ in,
                                                 ushort_t* __restrict__ out,
                                                 const int* __restrict__ flag) {
    const int i = (blockIdx.x * 256 + threadIdx.x) * 8;
    if (*flag) {
        *(float4*)&out[i] = *(const float4*)&((const ushort_t*)in)[i];
    } else {
        const float* p = (const float*)in + i;
        float4 f0 = *(const float4*)p;
        float4 f1 = *(const float4*)(p + 4);
        ushort_t t[8] = {f2b(f0.x), f2b(f0.y), f2b(f0.z), f2b(f0.w),
                         f2b(f1.x), f2b(f1.y), f2b(f1.z), f2b(f1.w)};
        *(float4*)&out[i] = *(const float4*)t;
    }
}

// ======== 256x128 triple-buffered phase pipeline (R4 post-mortem rebuild) ========
// R4's 8-phase failed on: (1) grid 384 = 1.5 rounds tail; (2) ds_read issued
// AFTER the barrier (barrier->ds-latency->MFMA serialized every phase);
// (3) prefetch depth ~1 phase. This version:
//  - BM=256 x BN=128 -> qkv grid 768 = 3 clean rounds, bt grid 256 = 1 round.
//  - LDS 3 buffers (96K A + 48K B = 144KB, 1 block/CU): tile t+2 staged during
//    tile t => each load has a full tile (~2 MFMA phases) of latency budget.
//  - Boundary gate: counted vmcnt(6) (t+2's 6 loads stay in flight, t+1's 6
//    proven landed) before the tile-end barrier; vmcnt(0) only at t=14.
//  - Phase = {8x ds_read_b128 (pre-barrier, wait at use) -> stage 3 GLD16 ->
//    barrier -> setprio(1) 16 MFMA setprio(0) -> [boundary vmcnt] -> barrier}.
//    2 phases (kk=0,1) per K-tile, 4 barriers/tile (R4: 8).
// Buffer safety: stage(t+2)->buf (t+2)%3; its last reader was tile t-1, done
// before the t-1 boundary barrier which precedes all tile-t stage issues. Reads
// of buf t%3 gated by all-waves vmcnt at t-1 boundary + barrier. All branches
// block-uniform. K-order per fragment = kloop64 (t asc, kk asc): bitwise-same.
__device__ __forceinline__ void pipe256x128(const ushort_t* __restrict__ A,
                                            const ushort_t* __restrict__ Bt,
                                            int row0, int col0,
                                            ushort_t* __restrict__ As,   // [3][256*64]
                                            ushort_t* __restrict__ Bs,   // [3][128*64]
                                            floatx4 acc[4][4], int tid) {
    const int lane = tid & 63, wave = tid >> 6;
    const int lane15 = lane & 15, quad = lane >> 4;
    const int s7 = lane15 & 7;                       // read-side swizzle key
    const int wm = wave >> 1, wn = wave & 1;         // 4M x 2N wave grid
    const int lrow = lane >> 3, lu = lane & 7, gu = lu ^ lrow;          // A staging
    const int brow = tid >> 3, bu = tid & 7, bgu = bu ^ (brow & 7);     // B staging

    // stage part h (0/1) of K-tile tt into buffer buf: 2 A-loads + 1 B-load.
    // All LDS dests are uniform-base + lane*16B (GLD16 requirement).
    auto stage_part = [&](int buf, int tt, int h) {
        ushort_t* Ad = As + buf * (256 * 64) + (h * 128 + wave * 16 + lrow) * 64 + lu * 8;
        const ushort_t* Asrc = A + (size_t)(row0 + h * 128 + wave * 16 + lrow) * CH + tt * 64 + gu * 8;
        GLD16(Asrc, Ad);
        GLD16(Asrc + 8 * CH, Ad + 8 * 64);           // row+8: same &7 -> same gu
        ushort_t* Bd = Bs + buf * (128 * 64) + (h * 64 + brow) * 64 + bu * 8;
        const ushort_t* Bsrc = Bt + (size_t)(col0 + h * 64 + brow) * CH + tt * 64 + bgu * 8;
        GLD16(Bsrc, Bd);
    };

    // prologue: stage tiles 0 and 1 (6 loads each)
    stage_part(0, 0, 0); stage_part(0, 0, 1);
    stage_part(1, 1, 0); stage_part(1, 1, 1);
    asm volatile("s_waitcnt vmcnt(6)" ::: "memory");  // tile 0's 6 landed
    __builtin_amdgcn_s_barrier();

    int buf = 0;
    for (int t = 0; t < 16; ++t) {
        const ushort_t* Ab = As + buf * (256 * 64) + (wm * 64) * 64;
        const ushort_t* Bb = Bs + buf * (128 * 64) + (wn * 64) * 64;
        int bnext = buf + 2; if (bnext >= 3) bnext -= 3;
        const bool pf = (t + 2 < 16);
        #pragma unroll
        for (int kk = 0; kk < 2; ++kk) {
            short8 af[4], bfr[4];
            #pragma unroll
            for (int i = 0; i < 4; i++)
                af[i] = *(const short8*)&Ab[(i * 16 + lane15) * 64 + (((kk * 4 + quad) ^ s7) * 8)];
            #pragma unroll
            for (int j = 0; j < 4; j++)
                bfr[j] = *(const short8*)&Bb[(j * 16 + lane15) * 64 + (((kk * 4 + quad) ^ s7) * 8)];
            if (pf) stage_part(bnext, t + 2, kk);
            __builtin_amdgcn_s_barrier();
            __builtin_amdgcn_s_setprio(1);
            #pragma unroll
            for (int i = 0; i < 4; i++)
                #pragma unroll
                for (int j = 0; j < 4; j++)
                    acc[i][j] = __builtin_amdgcn_mfma_f32_16x16x32_bf16(af[i], bfr[j], acc[i][j], 0, 0, 0);
            __builtin_amdgcn_s_setprio(0);
            if (kk == 1 && t < 15) {
                // gate tile t+1's reads: oldest 6 outstanding = t+1's stages
                if (pf) asm volatile("s_waitcnt vmcnt(6)" ::: "memory");
                else    asm volatile("s_waitcnt vmcnt(0)" ::: "memory");  // t=14 drain
            }
            __builtin_amdgcn_s_barrier();
        }
        buf = (buf == 2) ? 0 : buf + 1;
    }
}

// ---------------- fused QKV GEMM: [8192,1024] @ [3072,1024]^T + bias -------------
__global__ __launch_bounds__(512) void gemm_qkv8(const ushort_t* __restrict__ A,
                                                 const ushort_t* __restrict__ Bt,
                                                 const ushort_t* __restrict__ bias,
                                                 ushort_t* __restrict__ Qb,
                                                 ushort_t* __restrict__ Kb,
                                                 ushort_t* __restrict__ Vt,
                                                 float qscale) {
    __shared__ __align__(16) ushort_t As[3 * 256 * 64];   // 96 KB
    __shared__ __align__(16) ushort_t Bs[3 * 128 * 64];   // 48 KB
    const int tid = threadIdx.x;
    const int lane = tid & 63, wave = tid >> 6;
    const int lane15 = lane & 15, quad = lane >> 4;
    const int wm = wave >> 1, wn = wave & 1;
    // XCD-chunked bijective swizzle (grid 768, 768%8==0, cpx=96); col-fastest
    // within an XCD so consecutive blocks share the A panel (L2 hits).
    const int bid = blockIdx.x;
    const int bidl = (bid & 7) * 96 + (bid >> 3);
    const int rowblk = bidl / 24, colblk = bidl - rowblk * 24;
    const int row0 = rowblk * 256, col0 = colblk * 128;
    const int seg = col0 >> 10;                      // 0=Q 1=K 2=V (block-uniform)

    floatx4 acc[4][4];
    #pragma unroll
    for (int i = 0; i < 4; i++)
        #pragma unroll
        for (int j = 0; j < 4; j++) acc[i][j] = {0.f, 0.f, 0.f, 0.f};

    pipe256x128(A, Bt, row0, col0, As, Bs, acc, tid);

    #pragma unroll
    for (int j = 0; j < 4; j++) {
        const int col = col0 + wn * 64 + j * 16 + lane15;
        const float bv = b2f(bias[col]);
        #pragma unroll
        for (int i = 0; i < 4; i++) {
            const int rowb = row0 + wm * 64 + i * 16 + quad * 4;
            if (seg == 0) {
                #pragma unroll
                for (int r = 0; r < 4; r++)
                    Qb[(size_t)(rowb + r) * CH + col] = f2b((acc[i][j][r] + bv) * qscale);
            } else if (seg == 1) {
                const int c = col - 1024;
                #pragma unroll
                for (int r = 0; r < 4; r++)
                    Kb[(size_t)(rowb + r) * CH + c] = f2b(acc[i][j][r] + bv);
            } else {
                const int c = col - 2048;
                ushort_t pk[4];
                #pragma unroll
                for (int r = 0; r < 4; r++) pk[r] = f2b(acc[i][j][r] + bv);
                const int bb = rowb >> 11, tc = rowb & 2047;
                *(uint2*)&Vt[((size_t)bb * 1024 + c) * 2048 + tc] = *(const uint2*)pk;
            }
        }
    }
}

// ---------------- output GEMM: Out[8192,1024] = A @ WoT^T + bias -----------------
__global__ __launch_bounds__(512) void gemm_bt8(const ushort_t* __restrict__ A,
                                                const ushort_t* __restrict__ Bt,
                                                const ushort_t* __restrict__ bias,
                                                void* __restrict__ Out,
                                                const int* __restrict__ oflag) {
    __shared__ __align__(16) ushort_t As[3 * 256 * 64];   // 96 KB
    __shared__ __align__(16) ushort_t Bs[3 * 128 * 64];   // 48 KB
    const int om = *oflag;
    const int tid = threadIdx.x;
    const int lane = tid & 63, wave = tid >> 6;
    const int lane15 = lane & 15, quad = lane >> 4;
    const int wm = wave >> 1, wn = wave & 1;
    // grid 256 = exactly 1 round; cpx = 32
    const int bid = blockIdx.x;
    const int bidl = (bid & 7) * 32 + (bid >> 3);
    const int rowblk = bidl >> 3, colblk = bidl & 7;
    const int row0 = rowblk * 256, col0 = colblk * 128;

    floatx4 acc[4][4];
    #pragma unroll
    for (int i = 0; i < 4; i++)
        #pragma unroll
        for (int j = 0; j < 4; j++) acc[i][j] = {0.f, 0.f, 0.f, 0.f};

    pipe256x128(A, Bt, row0, col0, As, Bs, acc, tid);

    #pragma unroll
    for (int j = 0; j < 4; j++) {
        const int col = col0 + wn * 64 + j * 16 + lane15;
        const float bv = b2f(bias[col]);
        #pragma unroll
        for (int i = 0; i < 4; i++) {
            const int rowb = row0 + wm * 64 + i * 16 + quad * 4;
            #pragma unroll
            for (int r = 0; r < 4; r++) {
                const float val = acc[i][j][r] + bv;
                const size_t idx = (size_t)(rowb + r) * CH + col;
                if (om) ((ushort_t*)Out)[idx] = f2b(val);
                else    ((float*)Out)[idx] = val;
            }
        }
    }
}

// ---------------- flash attention (round-6 structure + S^T write path) -----------
// Keep: K/V dbuf, one barrier per tile, XCD-local (b,h) in bid&63, ones-MFMA
// rowsum, exp2 with scale folded into Q, swizzled K/V staging, Ps LDS round
// trip (decouples S from PV across waves). DO NOT add a second
// __launch_bounds__ arg (round-7 spill).
// R1 (kept): fast_exp2 raw v_exp_f32; Ps stride-64 4-bit XOR chunk swizzle
// (b64 writes and split-b64 PV reads both bank-conflict-free). Verified R2:
// attn dropped out of top-5 (<71.5 us, was 75.5).
__global__ __launch_bounds__(256) void attn_fwd(ushort_t* __restrict__ QY,
                                                const ushort_t* __restrict__ K,
                                                const ushort_t* __restrict__ Vt) {
    __shared__ __align__(16) ushort_t Ks[2][64 * 64];    // [buf][kv][d], swizzled
    __shared__ __align__(16) ushort_t Vs[2][64 * 64];    // [buf][d][kv], swizzled
    __shared__ __align__(16) ushort_t Ps[4 * 32 * 64];   // per-wave [q=32][kv=64], XOR-swizzled
    const int tid = threadIdx.x;
    const int lane = tid & 63, wave = tid >> 6;
    const int lane15 = lane & 15, quad = lane >> 4;
    const int sw = lane15 & 7;                            // read-side swizzle key
    const int bid = blockIdx.x;
    const int hb = bid & 63, qslot = bid >> 6;
    const int qb = 15 - qslot;
    const int h = hb & 15, b = hb >> 4;
    const int q0 = qb * 128;
    const size_t baseR = (size_t)b * SEQ * CH + h * HSZ;      // +t*CH+d (Q,K,Y)
    const size_t baseV = ((size_t)b * 1024 + h * HSZ) * SEQ;  // +d*SEQ+t (Vt)
    const int rg = lane >> 3, cg = (lane & 7) ^ rg;           // staging swizzle
    const int psBase = wave * 2048;                           // per-wave Ps region

    short8 qf[2][2];
    #pragma unroll
    for (int mm = 0; mm < 2; mm++) {
        const ushort_t* qp = QY + baseR + (size_t)(q0 + wave * 32 + mm * 16 + lane15) * CH + quad * 8;
        qf[mm][0] = *(const short8*)qp;
        qf[mm][1] = *(const short8*)(qp + 32);
    }
    const short8 kOnes = (short8)(short)0x3F80;  // bf16 1.0 x8

    floatx4 o[2][5];  // [mm][0..3]=O d-chunks, [4]=l (rowsum)
    #pragma unroll
    for (int mm = 0; mm < 2; mm++)
        #pragma unroll
        for (int j = 0; j < 5; j++) o[mm][j] = {0.f, 0.f, 0.f, 0.f};

    const int nkt = 2 * qb + 2;
    // preamble: stage tile 0 into buf 0
    #pragma unroll
    for (int l = wave; l < 8; l += 4) {
        GLD16(K  + baseR + (size_t)(l * 8 + rg) * CH + cg * 8, &Ks[0][l * 512]);
        GLD16(Vt + baseV + (size_t)(l * 8 + rg) * SEQ + cg * 8, &Vs[0][l * 512]);
    }

    for (int kt = 0; kt < nkt; kt++) {
        __syncthreads();  // staging of kt landed; all waves done with buf kt^1
        const int cur = kt & 1;
        if (kt + 1 < nkt) {
            const int kv1 = (kt + 1) * 64, nb = cur ^ 1;
            #pragma unroll
            for (int l = wave; l < 8; l += 4) {
                GLD16(K  + baseR + (size_t)(kv1 + l * 8 + rg) * CH + cg * 8, &Ks[nb][l * 512]);
                GLD16(Vt + baseV + (size_t)(l * 8 + rg) * SEQ + kv1 + cg * 8, &Vs[nb][l * 512]);
            }
        }
        const int kv0 = kt * 64;
        const int masked = (kt >= 2 * qb);

        // K fragments shared by both q-groups: a-frag of S^T = K[kv][d]
        short8 kf[4][2];
        #pragma unroll
        for (int g = 0; g < 4; g++) {
            kf[g][0] = *(const short8*)&Ks[cur][(g * 16 + lane15) * 64 + ((quad ^ sw) * 8)];
            kf[g][1] = *(const short8*)&Ks[cur][(g * 16 + lane15) * 64 + (((quad + 4) ^ sw) * 8)];
        }

        #pragma unroll
        for (int mm = 0; mm < 2; mm++) {
            const int qrow = q0 + wave * 32 + mm * 16 + lane15;
            const int rowOff = psBase + (mm * 16 + lane15) * 64;
            #pragma unroll
            for (int g = 0; g < 4; g++) {
                // z = S^T[kv = kv0+g*16+quad*4+r][q = qrow]
                floatx4 z = {0.f, 0.f, 0.f, 0.f};
                z = __builtin_amdgcn_mfma_f32_16x16x32_bf16(kf[g][0], qf[mm][0], z, 0, 0, 0);
                z = __builtin_amdgcn_mfma_f32_16x16x32_bf16(kf[g][1], qf[mm][1], z, 0, 0, 0);
                if (masked) {
                    #pragma unroll
                    for (int r = 0; r < 4; r++) {
                        const int col = kv0 + g * 16 + quad * 4 + r;
                        z[r] = (col <= qrow) ? z[r] : -1e30f;
                    }
                }
                // p = 2^z (raw v_exp_f32: 2^-1e30 -> 0 for masked lanes)
                const float p0 = fast_exp2(z[0]), p1 = fast_exp2(z[1]);
                const float p2 = fast_exp2(z[2]), p3 = fast_exp2(z[3]);
                unsigned int lo, hi;
                asm("v_cvt_pk_bf16_f32 %0, %1, %2" : "=v"(lo) : "v"(p0), "v"(p1));
                asm("v_cvt_pk_bf16_f32 %0, %1, %2" : "=v"(hi) : "v"(p2), "v"(p3));
                uint2 w; w.x = lo; w.y = hi;
                // logical 8B-chunk c = g*4+quad; physical = c ^ (row&15)
                *(uint2*)&Ps[rowOff + (((g * 4 + quad) ^ lane15) * 4)] = w;
            }
        }
        // Ps wave-private: lgkmcnt auto-wait orders write->read, no barrier

        #pragma unroll
        for (int kk = 0; kk < 2; kk++) {
            #pragma unroll
            for (int mm = 0; mm < 2; mm++) {
                // A-frag: logical chunks c0 = kk*8+quad*2, c0+1; swizzled apart
                const int rowOff = psBase + (mm * 16 + lane15) * 64;
                const int c0 = kk * 8 + quad * 2;
                short8 a;
                ((uint2*)&a)[0] = *(const uint2*)&Ps[rowOff + (((c0    ) ^ lane15) * 4)];
                ((uint2*)&a)[1] = *(const uint2*)&Ps[rowOff + (((c0 + 1) ^ lane15) * 4)];
                #pragma unroll
                for (int jn = 0; jn < 4; jn++) {
                    short8 bb = *(const short8*)&Vs[cur][(jn * 16 + lane15) * 64 + (((kk * 4 + quad) ^ sw) * 8)];
                    o[mm][jn] = __builtin_amdgcn_mfma_f32_16x16x32_bf16(a, bb, o[mm][jn], 0, 0, 0);
                }
                o[mm][4] = __builtin_amdgcn_mfma_f32_16x16x32_bf16(a, kOnes, o[mm][4], 0, 0, 0);
            }
        }
    }

    // epilogue: Y = O / l
    #pragma unroll
    for (int mm = 0; mm < 2; mm++)
        #pragma unroll
        for (int r = 0; r < 4; r++) {
            const int qrow = q0 + wave * 32 + mm * 16 + quad * 4 + r;
            const float rinv = 1.0f / fmaxf(o[mm][4][r], 1e-30f);
            #pragma unroll
            for (int jn = 0; jn < 4; jn++)
                QY[baseR + (size_t)qrow * CH + jn * 16 + lane15] = f2b(o[mm][jn][r] * rinv);
        }
}

extern "C" void kernel_launch(void* const* d_in, const int* in_sizes, int n_in,
                              void* d_out, int out_size, void* d_ws, size_t ws_size,
                              hipStream_t stream) {
    const void* x  = d_in[0];
    const void* Wk = d_in[1];
    const void* bk = d_in[2];
    const void* Wq = d_in[3];
    const void* bq = d_in[4];
    const void* Wv = d_in[5];
    const void* bv = d_in[6];
    const void* Wo = d_in[7];
    const void* bo = d_in[8];

    ushort_t* ws    = (ushort_t*)d_ws;
    int*      flag  = (int*)d_ws;
    ushort_t* biasC = ws + 2048;                    // 4x1024: q,k,v,o (contiguous)
    ushort_t* WqkvT = ws + 32768;                   // 3x1M contiguous: q,k,v
    ushort_t* WoT   = WqkvT + 3u * (1u << 20);
    ushort_t* xb    = ws + 4227072;                 // 8M elems bf16
    ushort_t* Qb    = ws + 12615680;                // 8M elems (becomes Y)
    ushort_t* Kb    = (ushort_t*)d_out;             // d_out scratch until final GEMM
    ushort_t* VtB   = Kb + (size_t)MROWS * CH;

    detect_dtype<<<1, 64, 0, stream>>>((const ushort_t*)x, flag);

    dim3 tgrid(32, 32, 4);
    convert_wt4<<<tgrid, 256, 0, stream>>>(Wq, Wk, Wv, Wo,
                                           WqkvT, WqkvT + (1u << 20), WqkvT + 2u * (1u << 20), WoT, flag);
    convert_bias4<<<16, 256, 0, stream>>>(bq, bk, bv, bo, biasC, flag);
    convert_x<<<MROWS * CH / (256 * 8), 256, 0, stream>>>(x, xb, flag);

    // scale = (1/sqrt(64)) * log2(e), folded into Q so attention uses exp2
    gemm_qkv8<<<dim3(768), 512, 0, stream>>>(xb, WqkvT, biasC, Qb, Kb, VtB, 0.1803368801f);

    attn_fwd<<<dim3(1024), 256, 0, stream>>>(Qb, Kb, VtB);

    gemm_bt8<<<dim3(256), 512, 0, stream>>>(Qb, WoT, biasC + 3072, d_out, flag);
}